// Round 1
// baseline (109.987 us; speedup 1.0000x reference)
//
#include <hip/hip_runtime.h>
#include <hip/hip_bf16.h>

#define BT    8192      // B*T tokens (4*2048)
#define SEQ_T 2048
#define DIN   1024
#define NH    16
#define NK    8
#define DH    64
#define DO    64

typedef __bf16 bf16;
typedef __attribute__((ext_vector_type(8))) __bf16 bf16x8;
typedef __attribute__((ext_vector_type(4))) __bf16 bf16x4;
typedef __attribute__((ext_vector_type(4))) float floatx4;

// ---------------------------------------------------------------------------
// Kernel 1 (unchanged, verified): scores + head-major bf16 xh + W transpose
// ---------------------------------------------------------------------------
__global__ __launch_bounds__(256) void prep_kernel(
    const float* __restrict__ x, const float* __restrict__ weight,
    const float* __restrict__ diag, const float* __restrict__ phi,
    float* __restrict__ scores_t, bf16* __restrict__ wt, bf16* __restrict__ xh)
{
  int blk = blockIdx.x, tid = threadIdx.x;
  if (blk < BT / 4) {
    // ---- scores + head-major bf16 copy: one wave per token ----
    int wave = tid >> 6, lane = tid & 63;
    int token = blk * 4 + wave;
    const floatx4* xr = (const floatx4*)(x + (size_t)token * DIN);
    const floatx4* dg = (const floatx4*)diag;
    floatx4 acc[NK];
#pragma unroll
    for (int k = 0; k < NK; k++) acc[k] = (floatx4){0.f, 0.f, 0.f, 0.f};
#pragma unroll
    for (int it = 0; it < 4; it++) {
      floatx4 xv = xr[it * 64 + lane];
      int col = it * 256 + lane * 4;
      int h = col >> 6, c = col & 63;
      bf16x4 cv;
      cv[0] = (bf16)xv[0]; cv[1] = (bf16)xv[1];
      cv[2] = (bf16)xv[2]; cv[3] = (bf16)xv[3];
      *(bf16x4*)(xh + ((size_t)h * BT + token) * 64 + c) = cv;
#pragma unroll
      for (int k = 0; k < NK; k++) {
        floatx4 dv = dg[k * 256 + it * 64 + lane];
        acc[k] += xv * dv;
      }
    }
    float r[NK];
#pragma unroll
    for (int k = 0; k < NK; k++)
      r[k] = (acc[k][0] + acc[k][1]) + (acc[k][2] + acc[k][3]);
#pragma unroll
    for (int k = 0; k < NK; k++) {
      float v = r[k];
#pragma unroll
      for (int off = 32; off >= 1; off >>= 1) v += __shfl_xor(v, off, 64);
      r[k] = v;
    }
    if (lane == 0) {
      int t = token & (SEQ_T - 1);
#pragma unroll
      for (int k = 0; k < NK; k++)
        scores_t[(size_t)k * BT + token] = phi[t * NK + k] + r[k];
    }
  } else {
    // ---- weight transpose: one (h,k) 64x64 tile per block, coalesced ----
    __shared__ bf16 tile[64 * 68];
    int hk = blk - BT / 4;
    const float* wsrc = weight + (size_t)hk * DH * DO;
#pragma unroll
    for (int it = 0; it < 4; it++) {
      int idx = it * 1024 + tid * 4;
      int i = idx >> 6, o = idx & 63;
      floatx4 v = *(const floatx4*)(wsrc + idx);
#pragma unroll
      for (int r = 0; r < 4; r++)
        tile[(o + r) * 68 + i] = (bf16)v[r];
    }
    __syncthreads();
#pragma unroll
    for (int it = 0; it < 4; it++) {
      int idx = it * 1024 + tid * 4;
      int o2 = idx >> 6, i2 = idx & 63;
      bf16x4 v = *(const bf16x4*)&tile[o2 * 68 + i2];
      *(bf16x4*)(wt + (size_t)hk * 4096 + idx) = v;
    }
  }
}

// ---------------------------------------------------------------------------
// Kernel 2 (v7): W-resident blocks + 4-group loop, double-buffered x/scores.
// Block = (h, nh, chunk-of-4-groups), 256 threads / 4 waves, grid = 512.
// LDS: W-half 32 KB + x dbuf 2x16 KB + scores dbuf 2x4 KB = 72 KB -> 2 blk/CU.
// Schedule per group i: issue g(i+1) global loads (T14 issue-early) -> MFMA
// phase on buf[i&1] -> ds_write g(i+1) into buf[(i+1)&1] (safe: last reader
// of that buffer finished before the PREVIOUS barrier) -> ONE __syncthreads
// -> global stores (drain under next group's compute, so the barrier's
// vmcnt(0) never waits on them).  XOR chunk swizzle identical to v6.
// ---------------------------------------------------------------------------
__global__ __launch_bounds__(256, 2) void moe_kernel(
    const bf16* __restrict__ xh, const bf16* __restrict__ wt,
    const float* __restrict__ scores_t, float* __restrict__ out)
{
  __shared__ bf16  wl[256 * 64];          // 32768 B (rows R = e*32 + o)
  __shared__ bf16  xl[2][128 * 64];       // 2 x 16384 B
  __shared__ float sl[2][NK * 128];       // 2 x 4096 B

  // XCD swizzle: 512 blocks = 8 XCD x 64; logical-consecutive blocks
  // (nh twins, consecutive chunks of same head) land on one XCD.
  int lid = ((blockIdx.x & 7) << 6) | (blockIdx.x >> 3);
  int nh    = lid & 1;            // col half (32 of the head's 64 out-cols)
  int chunk = (lid >> 1) & 15;    // 16 chunks x 4 groups of 128 tokens
  int h     = lid >> 5;           // 0..15
  int tid = threadIdx.x, lane = tid & 63, w = tid >> 6;
  int l15 = lane & 15, q = lane >> 4;

  const bf16*  xs = xh + ((size_t)h * BT + chunk * 512) * 64;
  const float* ss = scores_t + chunk * 512;
  int sk = tid >> 5, st4 = (tid & 31) * 4;

  // ---- prologue: issue W (8 x b128) + group-0 x (4 x b128) + scores ----
  bf16x8 wv[8];
#pragma unroll
  for (int it = 0; it < 8; it++) {
    int idx = it * 256 + tid, R = idx >> 3, c = idx & 7;
    int e = R >> 5, o = R & 31;
    wv[it] = *(const bf16x8*)(wt +
        (((size_t)(h * NK + e)) * DO + nh * 32 + o) * 64 + c * 8);
  }
  bf16x8 xv[4];
#pragma unroll
  for (int it = 0; it < 4; it++)
    xv[it] = *(const bf16x8*)(xs + (it * 256 + tid) * 8);
  floatx4 sv = *(const floatx4*)(ss + (size_t)sk * BT + st4);

  // ---- write W + buf0 (swizzled), publish ----
#pragma unroll
  for (int it = 0; it < 8; it++) {
    int idx = it * 256 + tid, R = idx >> 3, c = idx & 7;
    int pc = c ^ (R & 7);
    *(bf16x8*)(wl + R * 64 + pc * 8) = wv[it];
  }
#pragma unroll
  for (int it = 0; it < 4; it++) {
    int idx = it * 256 + tid, row = idx >> 3, c = idx & 7, pc = c ^ (row & 7);
    *(bf16x8*)(xl[0] + row * 64 + pc * 8) = xv[it];
  }
  *(floatx4*)(sl[0] + sk * 128 + st4) = sv;
  __syncthreads();

  // ---- B fragments: persist in VGPRs for all 4 groups ----
  int mh = w >> 1;                // token half (64 rows)
  int ns = w & 1;                 // 16-col slice within the 32-col half
  bf16x8 b[NK][2];
#pragma unroll
  for (int e = 0; e < NK; e++) {
    int R = e * 32 + ns * 16 + l15;
#pragma unroll
    for (int ki = 0; ki < 2; ki++) {
      int pc = (ki * 4 + q) ^ (R & 7);
      b[e][ki] = *(const bf16x8*)(wl + R * 64 + pc * 8);
    }
  }

#pragma unroll
  for (int i = 0; i < 4; i++) {
    const bf16*  xlc = xl[i & 1];
    const float* slc = sl[i & 1];

    // T14 issue-early: next group's global loads fly under the MFMA phase
    if (i < 3) {
#pragma unroll
      for (int it = 0; it < 4; it++)
        xv[it] = *(const bf16x8*)(xs + (i + 1) * (128 * 64) +
                                  (it * 256 + tid) * 8);
      sv = *(const floatx4*)(ss + (size_t)sk * BT + (i + 1) * 128 + st4);
    }

    // ---- compute: 4 m-tiles x 8 experts x 2 MFMA ----
    floatx4 yy[4];
#pragma unroll
    for (int m = 0; m < 4; m++) {
      int tr = mh * 64 + m * 16;
      int row = tr + l15;
      int p0 = q ^ (row & 7), p1 = (q + 4) ^ (row & 7);
      bf16x8 a0 = *(const bf16x8*)(xlc + row * 64 + p0 * 8);
      bf16x8 a1 = *(const bf16x8*)(xlc + row * 64 + p1 * 8);
      floatx4 y = (floatx4){0.f, 0.f, 0.f, 0.f};
#pragma unroll
      for (int e = 0; e < NK; e++) {
        floatx4 s4 = *(const floatx4*)(slc + e * 128 + tr + q * 4);
        floatx4 z = (floatx4){0.f, 0.f, 0.f, 0.f};
        z = __builtin_amdgcn_mfma_f32_16x16x32_bf16(a0, b[e][0], z, 0, 0, 0);
        z = __builtin_amdgcn_mfma_f32_16x16x32_bf16(a1, b[e][1], z, 0, 0, 0);
        y += s4 * z;
      }
      yy[m] = y;
    }

    // ---- write-late: publish next buffer, ONE barrier per group ----
    if (i < 3) {
#pragma unroll
      for (int it = 0; it < 4; it++) {
        int idx = it * 256 + tid, row = idx >> 3, c = idx & 7;
        int pc = c ^ (row & 7);
        *(bf16x8*)(xl[(i + 1) & 1] + row * 64 + pc * 8) = xv[it];
      }
      *(floatx4*)(sl[(i + 1) & 1] + sk * 128 + st4) = sv;
      __syncthreads();
    }

    // ---- stores AFTER the barrier: drain under next group's compute ----
#pragma unroll
    for (int m = 0; m < 4; m++) {
      int tr = mh * 64 + m * 16;
      int orow = (chunk * 4 + i) * 128 + tr + q * 4;
      float* op = out + (size_t)orow * (NH * DO) + h * DO +
                  nh * 32 + ns * 16 + l15;
#pragma unroll
      for (int r = 0; r < 4; r++)
        op[(size_t)r * (NH * DO)] = yy[m][r];
    }
  }
}

extern "C" void kernel_launch(void* const* d_in, const int* in_sizes, int n_in,
                              void* d_out, int out_size, void* d_ws, size_t ws_size,
                              hipStream_t stream) {
  const float* x      = (const float*)d_in[0];
  const float* weight = (const float*)d_in[1];
  const float* diag   = (const float*)d_in[2];
  const float* phi    = (const float*)d_in[3];
  float* out = (float*)d_out;

  // workspace: [0,1MiB) wt dense | [2MiB) scores_t 256KiB | [4MiB) xh 16MiB
  bf16*  wt       = (bf16*)d_ws;
  float* scores_t = (float*)((char*)d_ws + (2u << 20));
  bf16*  xh       = (bf16*)((char*)d_ws + (4u << 20));

  prep_kernel<<<BT / 4 + NH * NK, 256, 0, stream>>>(x, weight, diag, phi,
                                                    scores_t, wt, xh);
  // 16 heads x 2 col-halves x 16 chunks (4 token-groups each)
  moe_kernel<<<512, 256, 0, stream>>>(xh, wt, scores_t, out);
}